// Round 1
// 2142.041 us; speedup vs baseline: 1.0507x; 1.0507x over previous
//
#include <hip/hip_runtime.h>
#include <hip/hip_bf16.h>
#include <math.h>

#define H_DIM 2880
#define F_DIM 2880
#define GU_DIM 5760
#define NE 16
#define NT 1024
#define TOPK 4

typedef float f32x4 __attribute__((ext_vector_type(4)));
typedef __bf16 bf16x8 __attribute__((ext_vector_type(8)));

__device__ __forceinline__ unsigned short f2bf(float f) {
    union { float f; unsigned u; } v; v.f = f;
    return (unsigned short)((v.u + 0x8000u) >> 16);   // round-half-up to bf16
}
__device__ __forceinline__ unsigned pk2(float a, float b) {
    return (unsigned)f2bf(a) | ((unsigned)f2bf(b) << 16);
}
// async global->LDS, 16B per lane; LDS dest is wave-uniform base + lane*16
__device__ __forceinline__ void gload16(const void* gsrc, void* ldst) {
    __builtin_amdgcn_global_load_lds(
        (const __attribute__((address_space(1))) unsigned int*)gsrc,
        (__attribute__((address_space(3))) unsigned int*)ldst,
        16, 0, 0);
}

// ---------------- x -> bf16 cast (one-shot; removes A-convert from gemm1 loop) ----------------
__global__ __launch_bounds__(256) void castx_kernel(const float* __restrict__ x,
                                                    unsigned short* __restrict__ xb)
{
    int i = (blockIdx.x * 256 + threadIdx.x) * 8;
    float4 a = *(const float4*)(x + i);
    float4 b = *(const float4*)(x + i + 4);
    uint4 o;
    o.x = pk2(a.x, a.y); o.y = pk2(a.z, a.w);
    o.z = pk2(b.x, b.y); o.w = pk2(b.z, b.w);
    *(uint4*)(xb + i) = o;
}

// ---------------- router: logits -> top4 -> softmax -> counts ----------------
__global__ __launch_bounds__(64) void router_kernel(
    const float* __restrict__ x, const float* __restrict__ rw, const float* __restrict__ rb,
    int* counts, int* topk_idx, float* topk_score)
{
    int t = blockIdx.x, lane = threadIdx.x;
    const float* xr = x + (size_t)t * H_DIM;
    float acc[NE];
#pragma unroll
    for (int e = 0; e < NE; e++) acc[e] = 0.f;
    for (int h = lane; h < H_DIM; h += 64) {
        float xv = xr[h];
#pragma unroll
        for (int e = 0; e < NE; e++) acc[e] += xv * rw[e * H_DIM + h];
    }
    float lg[NE];
#pragma unroll
    for (int e = 0; e < NE; e++) {
        float v = acc[e];
#pragma unroll
        for (int off = 32; off > 0; off >>= 1) v += __shfl_down(v, off, 64);
        lg[e] = v;
    }
    if (lane == 0) {
#pragma unroll
        for (int e = 0; e < NE; e++) lg[e] += rb[e];
        int mask = 0; float tv[TOPK]; int ti[TOPK];
        for (int k = 0; k < TOPK; k++) {
            float best = -1e30f; int bi = 0;
            for (int e = 0; e < NE; e++)
                if (!((mask >> e) & 1) && lg[e] > best) { best = lg[e]; bi = e; }
            mask |= 1 << bi; tv[k] = best; ti[k] = bi;
        }
        float m = tv[0], s = 0.f, ex[TOPK];
        for (int k = 0; k < TOPK; k++) { ex[k] = expf(tv[k] - m); s += ex[k]; }
        float inv = 1.f / s;
        for (int k = 0; k < TOPK; k++) {
            topk_idx[t * TOPK + k] = ti[k];
            topk_score[t * TOPK + k] = ex[k] * inv;
            atomicAdd(&counts[ti[k]], 1);
        }
    }
}

__global__ void offsets_kernel(const int* counts, int* offsets) {
    if (threadIdx.x == 0 && blockIdx.x == 0) {
        int s = 0;
        for (int e = 0; e < NE; e++) { offsets[e] = s; s += counts[e]; }
        offsets[NE] = s;
    }
}

__global__ void scatter_kernel(const int* topk_idx, const float* topk_score,
                               const int* offsets, int* fills, int* entry, float* entry_score,
                               int* slot_map)
{
    int t = blockIdx.x * blockDim.x + threadIdx.x;
    if (t >= NT) return;
    for (int k = 0; k < TOPK; k++) {
        int e = topk_idx[t * TOPK + k];
        int pos = atomicAdd(&fills[e], 1);
        int i = offsets[e] + pos;
        entry[i] = t | (k << 16);
        entry_score[i] = topk_score[t * TOPK + k];
        slot_map[t * TOPK + k] = i;
    }
}

// ---------------- GEMM1: act = GLU(x[tokens] @ gate_up_w[e] + b) ----------------
// tile 128x128, BK=32, 4 waves. A: bf16 via global_load_lds (swizzled source).
// B: fp32 -> bf16 register staging (weights are fp32 in HBM).
__global__ __launch_bounds__(256, 2) void gemm1_kernel(
    const unsigned short* __restrict__ xb, const float* __restrict__ gw, const float* __restrict__ gb,
    const int* __restrict__ counts, const int* __restrict__ offsets,
    const int* __restrict__ entry, unsigned short* __restrict__ act)
{
    int e = blockIdx.z;
    int cnt = counts[e];
    int m0 = blockIdx.y * 128;
    if (m0 >= cnt) return;
    int n0 = blockIdx.x * 128;
    int off = offsets[e];

    __shared__ __align__(16) unsigned short As[128 * 32];  // [m][k] linear, chunk-swizzled content
    __shared__ __align__(16) unsigned short Bs[128 * 40];  // [n][k] stride 40, chunk-XOR swizzled
    __shared__ int toks[128];

    int tid = threadIdx.x;
    if (tid < 128) {
        int r = m0 + tid;
        toks[tid] = entry[off + (r < cnt ? r : 0)] & 0xFFFF;
    }
    __syncthreads();

    int wv = tid >> 6, lane = tid & 63;

    // A gload: wave wv stages rows 32*wv..32*wv+31; inst j covers 16 rows.
    // lane i -> row = base + (i>>2), phys chunk c = i&3; source chunk = c ^ ((row>>1)&3)
    int ar0 = 32 * wv + (lane >> 2);
    int ar1 = ar0 + 16;
    int ac = lane & 3;
    const unsigned short* asrc0 = xb + (size_t)toks[ar0] * H_DIM + 8 * (ac ^ ((ar0 >> 1) & 3));
    const unsigned short* asrc1 = xb + (size_t)toks[ar1] * H_DIM + 8 * (ac ^ ((ar1 >> 1) & 3));
    unsigned short* adst0 = &As[(32 * wv) * 32];
    unsigned short* adst1 = &As[(32 * wv + 16) * 32];

    // B staging: thread owns 4k x 4n block
    int n4 = tid & 31, kb = tid >> 5;
    const float* bptr = gw + (size_t)e * H_DIM * GU_DIM + (size_t)kb * 4 * GU_DIM + n0 + n4 * 4;

    int wm = (wv & 1) * 64, wn = (wv >> 1) * 64;
    int r16 = lane & 15, q = lane >> 4;

    f32x4 acc[4][4] = {};
    int a_rd[4], b_rd[4];
#pragma unroll
    for (int i = 0; i < 4; i++) {
        int m = wm + i * 16 + r16;
        a_rd[i] = m * 32 + ((q ^ ((m >> 1) & 3)) * 8);
        int n = wn + i * 16 + r16;
        b_rd[i] = n * 40 + ((q ^ ((n >> 2) & 3)) * 8);
    }
    int bwr[4];
#pragma unroll
    for (int c = 0; c < 4; c++) {
        int nl = n4 * 4 + c;
        bwr[c] = nl * 40 + (((kb >> 1) ^ ((nl >> 2) & 3)) * 8) + (kb & 1) * 4;
    }

    for (int k0 = 0; k0 < H_DIM; k0 += 32) {
        gload16(asrc0 + k0, adst0);
        gload16(asrc1 + k0, adst1);
        float bvf[4][4];
#pragma unroll
        for (int j = 0; j < 4; j++) {
            float4 tv = *(const float4*)(bptr + (size_t)(k0 + j) * GU_DIM);
            bvf[j][0] = tv.x; bvf[j][1] = tv.y; bvf[j][2] = tv.z; bvf[j][3] = tv.w;
        }
#pragma unroll
        for (int c = 0; c < 4; c++)
            *(uint2*)&Bs[bwr[c]] = make_uint2(pk2(bvf[0][c], bvf[1][c]), pk2(bvf[2][c], bvf[3][c]));
        __syncthreads();

        bf16x8 af[4], bq[4];
#pragma unroll
        for (int i = 0; i < 4; i++) af[i] = *(const bf16x8*)&As[a_rd[i]];
#pragma unroll
        for (int i = 0; i < 4; i++) bq[i] = *(const bf16x8*)&Bs[b_rd[i]];
#pragma unroll
        for (int mi = 0; mi < 4; mi++)
#pragma unroll
            for (int ni = 0; ni < 4; ni++)
                acc[mi][ni] = __builtin_amdgcn_mfma_f32_16x16x32_bf16(af[mi], bq[ni], acc[mi][ni], 0, 0, 0);
        __syncthreads();
    }

    // epilogue: bias + GLU (gate=even col, up=odd col), store bf16 act
    const float* gbp = gb + (size_t)e * GU_DIM;
#pragma unroll
    for (int ni = 0; ni < 4; ni++) {
        int col = n0 + wn + ni * 16 + r16;
        float bias = gbp[col];
#pragma unroll
        for (int mi = 0; mi < 4; mi++) {
#pragma unroll
            for (int r = 0; r < 4; r++) {
                float v = acc[mi][ni][r] + bias;
                float vo = __shfl_xor(v, 1, 64);
                float gate = (lane & 1) ? vo : v;
                float up   = (lane & 1) ? v  : vo;
                gate = fminf(gate, 7.0f);
                up = fminf(fmaxf(up, -7.0f), 7.0f);
                float glu = gate / (1.0f + expf(-1.702f * gate));
                float a = (up + 1.0f) * glu;
                int row = m0 + wm + mi * 16 + q * 4 + r;
                if (row < cnt && !(lane & 1))
                    act[(size_t)(off + row) * F_DIM + (col >> 1)] = f2bf(a);
            }
        }
    }
}

// ---------------- GEMM2: slot_out = score * (act @ down_w[e] + db), plain stores ----------------
__global__ __launch_bounds__(256, 2) void gemm2_kernel(
    const unsigned short* __restrict__ act, const float* __restrict__ dw, const float* __restrict__ db,
    const int* __restrict__ counts, const int* __restrict__ offsets,
    const float* __restrict__ entry_score, float* __restrict__ slot_out)
{
    int e = blockIdx.z;
    int cnt = counts[e];
    int m0 = blockIdx.y * 128;
    if (m0 >= cnt) return;
    int n0 = blockIdx.x * 128;
    int off = offsets[e];

    __shared__ __align__(16) unsigned short As[128 * 32];
    __shared__ __align__(16) unsigned short Bs[128 * 40];
    __shared__ float scs[128];

    int tid = threadIdx.x;
    if (tid < 128) {
        int r = m0 + tid;
        scs[tid] = entry_score[off + (r < cnt ? r : 0)];
    }
    __syncthreads();

    int wv = tid >> 6, lane = tid & 63;

    // A gload from act (bf16, slot rows are contiguous)
    int ar0 = 32 * wv + (lane >> 2);
    int ar1 = ar0 + 16;
    int ac = lane & 3;
    const unsigned short* asrc0 = act + (size_t)(off + m0 + ar0) * F_DIM + 8 * (ac ^ ((ar0 >> 1) & 3));
    const unsigned short* asrc1 = act + (size_t)(off + m0 + ar1) * F_DIM + 8 * (ac ^ ((ar1 >> 1) & 3));
    unsigned short* adst0 = &As[(32 * wv) * 32];
    unsigned short* adst1 = &As[(32 * wv + 16) * 32];

    int n4 = tid & 31, kb = tid >> 5;
    int ncol = n0 + n4 * 4;
    bool nval = ncol < H_DIM;              // last n-tile is ragged (2880 % 128 = 64)
    const float* bptr = dw + (size_t)e * F_DIM * H_DIM + (size_t)kb * 4 * H_DIM + ncol;

    int wm = (wv & 1) * 64, wn = (wv >> 1) * 64;
    int r16 = lane & 15, q = lane >> 4;

    f32x4 acc[4][4] = {};
    int a_rd[4], b_rd[4];
#pragma unroll
    for (int i = 0; i < 4; i++) {
        int m = wm + i * 16 + r16;
        a_rd[i] = m * 32 + ((q ^ ((m >> 1) & 3)) * 8);
        int n = wn + i * 16 + r16;
        b_rd[i] = n * 40 + ((q ^ ((n >> 2) & 3)) * 8);
    }
    int bwr[4];
#pragma unroll
    for (int c = 0; c < 4; c++) {
        int nl = n4 * 4 + c;
        bwr[c] = nl * 40 + (((kb >> 1) ^ ((nl >> 2) & 3)) * 8) + (kb & 1) * 4;
    }

    for (int k0 = 0; k0 < F_DIM; k0 += 32) {
        gload16(asrc0 + k0, adst0);
        gload16(asrc1 + k0, adst1);
        float bvf[4][4];
#pragma unroll
        for (int j = 0; j < 4; j++) {
            float4 tv = nval ? *(const float4*)(bptr + (size_t)(k0 + j) * H_DIM)
                             : make_float4(0.f, 0.f, 0.f, 0.f);
            bvf[j][0] = tv.x; bvf[j][1] = tv.y; bvf[j][2] = tv.z; bvf[j][3] = tv.w;
        }
#pragma unroll
        for (int c = 0; c < 4; c++)
            *(uint2*)&Bs[bwr[c]] = make_uint2(pk2(bvf[0][c], bvf[1][c]), pk2(bvf[2][c], bvf[3][c]));
        __syncthreads();

        bf16x8 af[4], bq[4];
#pragma unroll
        for (int i = 0; i < 4; i++) af[i] = *(const bf16x8*)&As[a_rd[i]];
#pragma unroll
        for (int i = 0; i < 4; i++) bq[i] = *(const bf16x8*)&Bs[b_rd[i]];
#pragma unroll
        for (int mi = 0; mi < 4; mi++)
#pragma unroll
            for (int ni = 0; ni < 4; ni++)
                acc[mi][ni] = __builtin_amdgcn_mfma_f32_16x16x32_bf16(af[mi], bq[ni], acc[mi][ni], 0, 0, 0);
        __syncthreads();
    }

    const float* dbp = db + (size_t)e * H_DIM;
#pragma unroll
    for (int ni = 0; ni < 4; ni++) {
        int col = n0 + wn + ni * 16 + r16;
        float bias = (col < H_DIM) ? dbp[col] : 0.f;
#pragma unroll
        for (int mi = 0; mi < 4; mi++) {
#pragma unroll
            for (int r = 0; r < 4; r++) {
                int lr = wm + mi * 16 + q * 4 + r;
                if (m0 + lr < cnt && col < H_DIM) {
                    float v = (acc[mi][ni][r] + bias) * scs[lr];
                    slot_out[(size_t)(off + m0 + lr) * H_DIM + col] = v;
                }
            }
        }
    }
}

// ---------------- gather: out[t] = sum of the token's 4 slot rows ----------------
__global__ __launch_bounds__(256) void gather_kernel(
    const float* __restrict__ slot_out, const int* __restrict__ slot_map,
    float* __restrict__ out)
{
    int t = blockIdx.x;
    int s0 = slot_map[t * TOPK + 0];
    int s1 = slot_map[t * TOPK + 1];
    int s2 = slot_map[t * TOPK + 2];
    int s3 = slot_map[t * TOPK + 3];
    const float* r0 = slot_out + (size_t)s0 * H_DIM;
    const float* r1 = slot_out + (size_t)s1 * H_DIM;
    const float* r2 = slot_out + (size_t)s2 * H_DIM;
    const float* r3 = slot_out + (size_t)s3 * H_DIM;
    float* op = out + (size_t)t * H_DIM;
    for (int h = threadIdx.x * 4; h < H_DIM; h += 1024) {
        f32x4 v = *(const f32x4*)(r0 + h) + *(const f32x4*)(r1 + h)
                + *(const f32x4*)(r2 + h) + *(const f32x4*)(r3 + h);
        *(f32x4*)(op + h) = v;
    }
}

// ---------------- launch ----------------
extern "C" void kernel_launch(void* const* d_in, const int* in_sizes, int n_in,
                              void* d_out, int out_size, void* d_ws, size_t ws_size,
                              hipStream_t stream)
{
    const float* x  = (const float*)d_in[0];
    const float* rw = (const float*)d_in[1];
    const float* rb = (const float*)d_in[2];
    const float* gw = (const float*)d_in[3];
    const float* gb = (const float*)d_in[4];
    const float* dw = (const float*)d_in[5];
    const float* db = (const float*)d_in[6];
    float* out = (float*)d_out;

    char* ws = (char*)d_ws;
    int*   counts      = (int*)(ws);
    int*   fills       = (int*)(ws + 64);
    int*   offsets     = (int*)(ws + 128);
    int*   topk_idx    = (int*)(ws + 256);
    float* topk_score  = (float*)(ws + 16640);
    int*   entry       = (int*)(ws + 33024);
    float* entry_score = (float*)(ws + 49408);
    int*   slot_map    = (int*)(ws + 65792);
    unsigned short* act = (unsigned short*)(ws + 131072);             // 4224 x 2880 bf16 (128-row slack for gload overread)
    unsigned short* xb  = (unsigned short*)(ws + 131072 + 24330240);  // 1024 x 2880 bf16
    float* slot_out     = (float*)(ws + 30359552);                    // 4096 x 2880 f32

    hipMemsetAsync(ws, 0, 256, stream);   // counts + fills

    castx_kernel<<<1440, 256, 0, stream>>>(x, xb);
    router_kernel<<<NT, 64, 0, stream>>>(x, rw, rb, counts, topk_idx, topk_score);
    offsets_kernel<<<1, 32, 0, stream>>>(counts, offsets);
    scatter_kernel<<<4, 256, 0, stream>>>(topk_idx, topk_score, offsets, fills, entry, entry_score, slot_map);
    gemm1_kernel<<<dim3(45, 8, NE), 256, 0, stream>>>(xb, gw, gb, counts, offsets, entry, act);
    gemm2_kernel<<<dim3(23, 8, NE), 256, 0, stream>>>(act, dw, db, counts, offsets, entry_score, slot_out);
    gather_kernel<<<NT, 256, 0, stream>>>(slot_out, slot_map, out);
}

// Round 2
// 2096.890 us; speedup vs baseline: 1.0734x; 1.0215x over previous
//
#include <hip/hip_runtime.h>
#include <hip/hip_bf16.h>
#include <math.h>

#define H_DIM 2880
#define F_DIM 2880
#define GU_DIM 5760
#define NE 16
#define NT 1024
#define TOPK 4
#define NIT (H_DIM / 32)   // 90 K-steps for both GEMMs (F_DIM == H_DIM)

typedef float f32x4 __attribute__((ext_vector_type(4)));
typedef __bf16 bf16x8 __attribute__((ext_vector_type(8)));

__device__ __forceinline__ unsigned short f2bf(float f) {
    union { float f; unsigned u; } v; v.f = f;
    return (unsigned short)((v.u + 0x8000u) >> 16);   // round-half-up to bf16
}
__device__ __forceinline__ unsigned pk2(float a, float b) {
    return (unsigned)f2bf(a) | ((unsigned)f2bf(b) << 16);
}
// async global->LDS, 16B per lane; LDS dest is wave-uniform base + lane*16
__device__ __forceinline__ void gload16(const void* gsrc, void* ldst) {
    __builtin_amdgcn_global_load_lds(
        (const __attribute__((address_space(1))) unsigned int*)gsrc,
        (__attribute__((address_space(3))) unsigned int*)ldst,
        16, 0, 0);
}

// ---------------- x -> bf16 cast ----------------
__global__ __launch_bounds__(256) void castx_kernel(const float* __restrict__ x,
                                                    unsigned short* __restrict__ xb)
{
    int i = (blockIdx.x * 256 + threadIdx.x) * 8;
    float4 a = *(const float4*)(x + i);
    float4 b = *(const float4*)(x + i + 4);
    uint4 o;
    o.x = pk2(a.x, a.y); o.y = pk2(a.z, a.w);
    o.z = pk2(b.x, b.y); o.w = pk2(b.z, b.w);
    *(uint4*)(xb + i) = o;
}

// ---------------- router ----------------
__global__ __launch_bounds__(64) void router_kernel(
    const float* __restrict__ x, const float* __restrict__ rw, const float* __restrict__ rb,
    int* counts, int* topk_idx, float* topk_score)
{
    int t = blockIdx.x, lane = threadIdx.x;
    const float* xr = x + (size_t)t * H_DIM;
    float acc[NE];
#pragma unroll
    for (int e = 0; e < NE; e++) acc[e] = 0.f;
    for (int h = lane; h < H_DIM; h += 64) {
        float xv = xr[h];
#pragma unroll
        for (int e = 0; e < NE; e++) acc[e] += xv * rw[e * H_DIM + h];
    }
    float lg[NE];
#pragma unroll
    for (int e = 0; e < NE; e++) {
        float v = acc[e];
#pragma unroll
        for (int off = 32; off > 0; off >>= 1) v += __shfl_down(v, off, 64);
        lg[e] = v;
    }
    if (lane == 0) {
#pragma unroll
        for (int e = 0; e < NE; e++) lg[e] += rb[e];
        int mask = 0; float tv[TOPK]; int ti[TOPK];
        for (int k = 0; k < TOPK; k++) {
            float best = -1e30f; int bi = 0;
            for (int e = 0; e < NE; e++)
                if (!((mask >> e) & 1) && lg[e] > best) { best = lg[e]; bi = e; }
            mask |= 1 << bi; tv[k] = best; ti[k] = bi;
        }
        float m = tv[0], s = 0.f, ex[TOPK];
        for (int k = 0; k < TOPK; k++) { ex[k] = expf(tv[k] - m); s += ex[k]; }
        float inv = 1.f / s;
        for (int k = 0; k < TOPK; k++) {
            topk_idx[t * TOPK + k] = ti[k];
            topk_score[t * TOPK + k] = ex[k] * inv;
            atomicAdd(&counts[ti[k]], 1);
        }
    }
}

__global__ void offsets_kernel(const int* counts, int* offsets) {
    if (threadIdx.x == 0 && blockIdx.x == 0) {
        int s = 0;
        for (int e = 0; e < NE; e++) { offsets[e] = s; s += counts[e]; }
        offsets[NE] = s;
    }
}

__global__ void scatter_kernel(const int* topk_idx, const float* topk_score,
                               const int* offsets, int* fills, int* entry, float* entry_score,
                               int* slot_map)
{
    int t = blockIdx.x * blockDim.x + threadIdx.x;
    if (t >= NT) return;
    for (int k = 0; k < TOPK; k++) {
        int e = topk_idx[t * TOPK + k];
        int pos = atomicAdd(&fills[e], 1);
        int i = offsets[e] + pos;
        entry[i] = t | (k << 16);
        entry_score[i] = topk_score[t * TOPK + k];
        slot_map[t * TOPK + k] = i;
    }
}

// ---------------- GEMM1: act = GLU(x[tokens] @ gate_up_w[e] + b) ----------------
// tile 256x128, BK=32, 8 waves (4m x 2n), LDS double-buffered, 1 barrier/K-step.
// A: bf16 via global_load_lds. B: fp32 -> bf16 register staging by threads 0-255.
__global__ __launch_bounds__(512) void gemm1_kernel(
    const unsigned short* __restrict__ xb, const float* __restrict__ gw, const float* __restrict__ gb,
    const int* __restrict__ counts, const int* __restrict__ offsets,
    const int* __restrict__ entry, unsigned short* __restrict__ act)
{
    int e = blockIdx.z;
    int cnt = counts[e];
    int m0 = blockIdx.y * 256;
    if (m0 >= cnt) return;
    int n0 = blockIdx.x * 128;
    int off = offsets[e];

    __shared__ __align__(16) unsigned short As[2][256 * 32];  // 16KB x2
    __shared__ __align__(16) unsigned short Bs[2][128 * 40];  // 10KB x2
    __shared__ int toks[256];

    int tid = threadIdx.x;
    if (tid < 256) {
        int r = m0 + tid;
        toks[tid] = entry[off + (r < cnt ? r : 0)] & 0xFFFF;
    }
    __syncthreads();

    int wv = tid >> 6, lane = tid & 63;

    // A gload: wave wv stages rows 32*wv..32*wv+31 (2 insts x 16 rows x 64B)
    int ar0 = 32 * wv + (lane >> 2);
    int ar1 = ar0 + 16;
    int ac = lane & 3;
    const unsigned short* asrc0 = xb + (size_t)toks[ar0] * H_DIM + 8 * (ac ^ ((ar0 >> 1) & 3));
    const unsigned short* asrc1 = xb + (size_t)toks[ar1] * H_DIM + 8 * (ac ^ ((ar1 >> 1) & 3));
    int aoff0 = (32 * wv) * 32;
    int aoff1 = (32 * wv + 16) * 32;

    // B staging (threads 0-255): thread owns 4k x 4n block
    int n4 = tid & 31, kb = (tid >> 5) & 7;
    const float* bptr = gw + (size_t)e * H_DIM * GU_DIM + (size_t)kb * 4 * GU_DIM + n0 + n4 * 4;
    int bwr[4];
#pragma unroll
    for (int c = 0; c < 4; c++) {
        int nl = n4 * 4 + c;
        bwr[c] = nl * 40 + (((kb >> 1) ^ ((nl >> 2) & 3)) * 8) + (kb & 1) * 4;
    }

    int wm = (wv >> 1) * 64, wn = (wv & 1) * 64;
    int r16 = lane & 15, q = lane >> 4;

    f32x4 acc[4][4] = {};
    int a_rd[4], b_rd[4];
#pragma unroll
    for (int i = 0; i < 4; i++) {
        int m = wm + i * 16 + r16;
        a_rd[i] = m * 32 + ((q ^ ((m >> 1) & 3)) * 8);
        int n = wn + i * 16 + r16;
        b_rd[i] = n * 40 + ((q ^ ((n >> 2) & 3)) * 8);
    }

    // prologue: stage tile 0 into buffer 0
    gload16(asrc0, &As[0][aoff0]);
    gload16(asrc1, &As[0][aoff1]);
    if (tid < 256) {
        float bvf[4][4];
#pragma unroll
        for (int j = 0; j < 4; j++) {
            float4 tv = *(const float4*)(bptr + (size_t)j * GU_DIM);
            bvf[j][0] = tv.x; bvf[j][1] = tv.y; bvf[j][2] = tv.z; bvf[j][3] = tv.w;
        }
#pragma unroll
        for (int c = 0; c < 4; c++)
            *(uint2*)&Bs[0][bwr[c]] = make_uint2(pk2(bvf[0][c], bvf[1][c]), pk2(bvf[2][c], bvf[3][c]));
    }
    __syncthreads();

    for (int it = 0; it < NIT; it++) {
        int cur = it & 1, nxt = cur ^ 1;
        int k1 = (it + 1) * 32;
        bool more = (it + 1 < NIT);
        float bvf[4][4];
        if (more) {
            gload16(asrc0 + k1, &As[nxt][aoff0]);
            gload16(asrc1 + k1, &As[nxt][aoff1]);
            if (tid < 256) {
#pragma unroll
                for (int j = 0; j < 4; j++) {
                    float4 tv = *(const float4*)(bptr + (size_t)(k1 + j) * GU_DIM);
                    bvf[j][0] = tv.x; bvf[j][1] = tv.y; bvf[j][2] = tv.z; bvf[j][3] = tv.w;
                }
            }
        }
        bf16x8 af[4], bq[4];
#pragma unroll
        for (int i = 0; i < 4; i++) af[i] = *(const bf16x8*)&As[cur][a_rd[i]];
#pragma unroll
        for (int i = 0; i < 4; i++) bq[i] = *(const bf16x8*)&Bs[cur][b_rd[i]];
#pragma unroll
        for (int mi = 0; mi < 4; mi++)
#pragma unroll
            for (int ni = 0; ni < 4; ni++)
                acc[mi][ni] = __builtin_amdgcn_mfma_f32_16x16x32_bf16(af[mi], bq[ni], acc[mi][ni], 0, 0, 0);
        if (more && tid < 256) {
#pragma unroll
            for (int c = 0; c < 4; c++)
                *(uint2*)&Bs[nxt][bwr[c]] = make_uint2(pk2(bvf[0][c], bvf[1][c]), pk2(bvf[2][c], bvf[3][c]));
        }
        __syncthreads();
    }

    // epilogue: bias + GLU (gate=even col, up=odd col), store bf16 act
    const float* gbp = gb + (size_t)e * GU_DIM;
#pragma unroll
    for (int ni = 0; ni < 4; ni++) {
        int col = n0 + wn + ni * 16 + r16;
        float bias = gbp[col];
#pragma unroll
        for (int mi = 0; mi < 4; mi++) {
#pragma unroll
            for (int r = 0; r < 4; r++) {
                float v = acc[mi][ni][r] + bias;
                float vo = __shfl_xor(v, 1, 64);
                float gate = (lane & 1) ? vo : v;
                float up   = (lane & 1) ? v  : vo;
                gate = fminf(gate, 7.0f);
                up = fminf(fmaxf(up, -7.0f), 7.0f);
                float glu = gate / (1.0f + expf(-1.702f * gate));
                float a = (up + 1.0f) * glu;
                int row = m0 + wm + mi * 16 + q * 4 + r;
                if (row < cnt && !(lane & 1))
                    act[(size_t)(off + row) * F_DIM + (col >> 1)] = f2bf(a);
            }
        }
    }
}

// ---------------- GEMM2: slot_out = score * (act @ down_w[e] + db) ----------------
__global__ __launch_bounds__(512) void gemm2_kernel(
    const unsigned short* __restrict__ act, const float* __restrict__ dw, const float* __restrict__ db,
    const int* __restrict__ counts, const int* __restrict__ offsets,
    const float* __restrict__ entry_score, float* __restrict__ slot_out)
{
    int e = blockIdx.z;
    int cnt = counts[e];
    int m0 = blockIdx.y * 256;
    if (m0 >= cnt) return;
    int n0 = blockIdx.x * 128;
    int off = offsets[e];

    __shared__ __align__(16) unsigned short As[2][256 * 32];
    __shared__ __align__(16) unsigned short Bs[2][128 * 40];
    __shared__ float scs[256];

    int tid = threadIdx.x;
    if (tid < 256) {
        int r = m0 + tid;
        scs[tid] = entry_score[off + (r < cnt ? r : 0)];
    }
    __syncthreads();

    int wv = tid >> 6, lane = tid & 63;

    int ar0 = 32 * wv + (lane >> 2);
    int ar1 = ar0 + 16;
    int ac = lane & 3;
    const unsigned short* asrc0 = act + (size_t)(off + m0 + ar0) * F_DIM + 8 * (ac ^ ((ar0 >> 1) & 3));
    const unsigned short* asrc1 = act + (size_t)(off + m0 + ar1) * F_DIM + 8 * (ac ^ ((ar1 >> 1) & 3));
    int aoff0 = (32 * wv) * 32;
    int aoff1 = (32 * wv + 16) * 32;

    int n4 = tid & 31, kb = (tid >> 5) & 7;
    int ncol = n0 + n4 * 4;
    bool nval = ncol < H_DIM;              // last n-tile ragged (2880 % 128 = 64)
    const float* bptr = dw + (size_t)e * F_DIM * H_DIM + (size_t)kb * 4 * H_DIM + ncol;
    int bwr[4];
#pragma unroll
    for (int c = 0; c < 4; c++) {
        int nl = n4 * 4 + c;
        bwr[c] = nl * 40 + (((kb >> 1) ^ ((nl >> 2) & 3)) * 8) + (kb & 1) * 4;
    }

    int wm = (wv >> 1) * 64, wn = (wv & 1) * 64;
    int r16 = lane & 15, q = lane >> 4;

    f32x4 acc[4][4] = {};
    int a_rd[4], b_rd[4];
#pragma unroll
    for (int i = 0; i < 4; i++) {
        int m = wm + i * 16 + r16;
        a_rd[i] = m * 32 + ((q ^ ((m >> 1) & 3)) * 8);
        int n = wn + i * 16 + r16;
        b_rd[i] = n * 40 + ((q ^ ((n >> 2) & 3)) * 8);
    }

    // prologue
    gload16(asrc0, &As[0][aoff0]);
    gload16(asrc1, &As[0][aoff1]);
    if (tid < 256) {
        float bvf[4][4];
#pragma unroll
        for (int j = 0; j < 4; j++) {
            float4 tv = nval ? *(const float4*)(bptr + (size_t)j * H_DIM)
                             : make_float4(0.f, 0.f, 0.f, 0.f);
            bvf[j][0] = tv.x; bvf[j][1] = tv.y; bvf[j][2] = tv.z; bvf[j][3] = tv.w;
        }
#pragma unroll
        for (int c = 0; c < 4; c++)
            *(uint2*)&Bs[0][bwr[c]] = make_uint2(pk2(bvf[0][c], bvf[1][c]), pk2(bvf[2][c], bvf[3][c]));
    }
    __syncthreads();

    for (int it = 0; it < NIT; it++) {
        int cur = it & 1, nxt = cur ^ 1;
        int k1 = (it + 1) * 32;
        bool more = (it + 1 < NIT);
        float bvf[4][4];
        if (more) {
            gload16(asrc0 + k1, &As[nxt][aoff0]);
            gload16(asrc1 + k1, &As[nxt][aoff1]);
            if (tid < 256) {
#pragma unroll
                for (int j = 0; j < 4; j++) {
                    float4 tv = nval ? *(const float4*)(bptr + (size_t)(k1 + j) * H_DIM)
                                     : make_float4(0.f, 0.f, 0.f, 0.f);
                    bvf[j][0] = tv.x; bvf[j][1] = tv.y; bvf[j][2] = tv.z; bvf[j][3] = tv.w;
                }
            }
        }
        bf16x8 af[4], bq[4];
#pragma unroll
        for (int i = 0; i < 4; i++) af[i] = *(const bf16x8*)&As[cur][a_rd[i]];
#pragma unroll
        for (int i = 0; i < 4; i++) bq[i] = *(const bf16x8*)&Bs[cur][b_rd[i]];
#pragma unroll
        for (int mi = 0; mi < 4; mi++)
#pragma unroll
            for (int ni = 0; ni < 4; ni++)
                acc[mi][ni] = __builtin_amdgcn_mfma_f32_16x16x32_bf16(af[mi], bq[ni], acc[mi][ni], 0, 0, 0);
        if (more && tid < 256) {
#pragma unroll
            for (int c = 0; c < 4; c++)
                *(uint2*)&Bs[nxt][bwr[c]] = make_uint2(pk2(bvf[0][c], bvf[1][c]), pk2(bvf[2][c], bvf[3][c]));
        }
        __syncthreads();
    }

    const float* dbp = db + (size_t)e * H_DIM;
#pragma unroll
    for (int ni = 0; ni < 4; ni++) {
        int col = n0 + wn + ni * 16 + r16;
        float bias = (col < H_DIM) ? dbp[col] : 0.f;
#pragma unroll
        for (int mi = 0; mi < 4; mi++) {
#pragma unroll
            for (int r = 0; r < 4; r++) {
                int lr = wm + mi * 16 + q * 4 + r;
                if (m0 + lr < cnt && col < H_DIM) {
                    float v = (acc[mi][ni][r] + bias) * scs[lr];
                    slot_out[(size_t)(off + m0 + lr) * H_DIM + col] = v;
                }
            }
        }
    }
}

// ---------------- gather ----------------
__global__ __launch_bounds__(256) void gather_kernel(
    const float* __restrict__ slot_out, const int* __restrict__ slot_map,
    float* __restrict__ out)
{
    int t = blockIdx.x;
    int s0 = slot_map[t * TOPK + 0];
    int s1 = slot_map[t * TOPK + 1];
    int s2 = slot_map[t * TOPK + 2];
    int s3 = slot_map[t * TOPK + 3];
    const float* r0 = slot_out + (size_t)s0 * H_DIM;
    const float* r1 = slot_out + (size_t)s1 * H_DIM;
    const float* r2 = slot_out + (size_t)s2 * H_DIM;
    const float* r3 = slot_out + (size_t)s3 * H_DIM;
    float* op = out + (size_t)t * H_DIM;
    for (int h = threadIdx.x * 4; h < H_DIM; h += 1024) {
        f32x4 v = *(const f32x4*)(r0 + h) + *(const f32x4*)(r1 + h)
                + *(const f32x4*)(r2 + h) + *(const f32x4*)(r3 + h);
        *(f32x4*)(op + h) = v;
    }
}

// ---------------- launch ----------------
extern "C" void kernel_launch(void* const* d_in, const int* in_sizes, int n_in,
                              void* d_out, int out_size, void* d_ws, size_t ws_size,
                              hipStream_t stream)
{
    const float* x  = (const float*)d_in[0];
    const float* rw = (const float*)d_in[1];
    const float* rb = (const float*)d_in[2];
    const float* gw = (const float*)d_in[3];
    const float* gb = (const float*)d_in[4];
    const float* dw = (const float*)d_in[5];
    const float* db = (const float*)d_in[6];
    float* out = (float*)d_out;

    char* ws = (char*)d_ws;
    int*   counts      = (int*)(ws);
    int*   fills       = (int*)(ws + 64);
    int*   offsets     = (int*)(ws + 128);
    int*   topk_idx    = (int*)(ws + 256);
    float* topk_score  = (float*)(ws + 16640);
    int*   entry       = (int*)(ws + 33024);
    float* entry_score = (float*)(ws + 49408);
    int*   slot_map    = (int*)(ws + 65792);
    unsigned short* act = (unsigned short*)(ws + 131072);   // 4352 x 2880 bf16 (256-row slack for gload overread)
    unsigned short* xb  = (unsigned short*)(ws + 25198592); // 1024 x 2880 bf16
    float* slot_out     = (float*)(ws + 31096832);          // 4096 x 2880 f32

    hipMemsetAsync(ws, 0, 256, stream);   // counts + fills

    castx_kernel<<<1440, 256, 0, stream>>>(x, xb);
    router_kernel<<<NT, 64, 0, stream>>>(x, rw, rb, counts, topk_idx, topk_score);
    offsets_kernel<<<1, 32, 0, stream>>>(counts, offsets);
    scatter_kernel<<<4, 256, 0, stream>>>(topk_idx, topk_score, offsets, fills, entry, entry_score, slot_map);
    gemm1_kernel<<<dim3(45, 4, NE), 512, 0, stream>>>(xb, gw, gb, counts, offsets, entry, act);
    gemm2_kernel<<<dim3(23, 4, NE), 512, 0, stream>>>(act, dw, db, counts, offsets, entry_score, slot_out);
    gather_kernel<<<NT, 256, 0, stream>>>(slot_out, slot_map, out);
}